// Round 7
// baseline (262.245 us; speedup 1.0000x reference)
//
#include <hip/hip_runtime.h>

typedef unsigned short ushort_t;
typedef __attribute__((ext_vector_type(8))) short bf16x8;
typedef __attribute__((ext_vector_type(4))) float f32x4;

#define DMODEL 1024
#define NHEADS 16
#define DK 64
#define BS 2
#define TS 2048
#define MROWS (BS * TS)  // 4096

// 0.125 * log2(e): folded into Q so attention uses raw v_exp_f32 (exp2)
#define QSCALE 0.1803368801111204f

__device__ __forceinline__ ushort_t f2bf(float x) {
    unsigned u = __float_as_uint(x);
    return (ushort_t)((u + 0x7FFFu + ((u >> 16) & 1u)) >> 16);  // RNE
}

__device__ __forceinline__ unsigned cvt_pk_bf16(float lo, float hi) {
    unsigned r;
    asm("v_cvt_pk_bf16_f32 %0, %1, %2" : "=v"(r) : "v"(lo), "v"(hi));
    return r;
}

__device__ __forceinline__ void gload_lds16(const void* g, void* l) {
    __builtin_amdgcn_global_load_lds(
        (const __attribute__((address_space(1))) unsigned*)g,
        (__attribute__((address_space(3))) unsigned*)l, 16, 0, 0);
}

// ---------------------------------------------------------------------------
// fp32 -> bf16 cast: 3 activations (4M each) + 4 weights (1M each).
// ---------------------------------------------------------------------------
__global__ __launch_bounds__(256) void cvt_all_kernel(
    const float* __restrict__ q, const float* __restrict__ k,
    const float* __restrict__ v, const float* __restrict__ wq,
    const float* __restrict__ wk, const float* __restrict__ wv,
    const float* __restrict__ wo, ushort_t* __restrict__ dst)
{
    const int i = blockIdx.x * 256 + threadIdx.x;  // float4 index
    const float4* s;
    int off;
    if (i < (1 << 20))      { s = (const float4*)q; off = i; }
    else if (i < (2 << 20)) { s = (const float4*)k; off = i - (1 << 20); }
    else if (i < (3 << 20)) { s = (const float4*)v; off = i - (2 << 20); }
    else {
        const int j = i - (3 << 20);
        const int w = j >> 18;
        off = j & 0x3FFFF;
        s = (w == 0) ? (const float4*)wq : (w == 1) ? (const float4*)wk
          : (w == 2) ? (const float4*)wv : (const float4*)wo;
    }
    const float4 x = s[off];
    ushort4 o;
    o.x = f2bf(x.x); o.y = f2bf(x.y); o.z = f2bf(x.z); o.w = f2bf(x.w);
    ((ushort4*)dst)[i] = o;
}

// ---------------------------------------------------------------------------
// GEMM core: 128x128 tile, 4 waves each 64x64 (4x4 frags), BK=32.
// 3-buffer LDS, 2-tile-ahead prefetch, COUNTED vmcnt(4) + raw s_barrier
// (T4): next tile's 4 global_load_lds stay in flight across the barrier;
// only the last iteration drains to 0.
// SWAP=false: acc = mfma(a, b)  -> lane holds C[t-frag=g4r][col=c]
// SWAP=true : acc = mfma(b, a)  -> lane holds C[t=c][col-frag=g4r]
// ---------------------------------------------------------------------------
template <bool SWAP>
__device__ __forceinline__ void gemm_body128(
    const ushort_t* __restrict__ A, const ushort_t* __restrict__ W,
    ushort_t (&Asm)[3][4096], ushort_t (&Bsm)[3][4096],
    f32x4 (&acc)[4][4], int row0, int col0, int w, int lane)
{
    const int c = lane & 15, g = lane >> 4;
    const int wr = w >> 1, wc = w & 1;
    const int lr = lane >> 2;          // 0..15 staging row within 16-chunk
    const int lcb = (lane & 3) * 8;    // 16B chunk within 64B row
    const ushort_t* Ab = &A[(size_t)(row0 + w * 32 + lr) * DMODEL + lcb];
    const ushort_t* Wb = &W[(size_t)(col0 + w * 32 + lr) * DMODEL + lcb];
    ushort_t* A0 = &Asm[0][0];
    ushort_t* B0 = &Bsm[0][0];

#define GSTAGE(buf, k0_) do { \
    gload_lds16(Ab + (k0_), A0 + (buf) * 4096 + (w * 32) * 32); \
    gload_lds16(Ab + 16 * DMODEL + (k0_), A0 + (buf) * 4096 + (w * 32 + 16) * 32); \
    gload_lds16(Wb + (k0_), B0 + (buf) * 4096 + (w * 32) * 32); \
    gload_lds16(Wb + 16 * DMODEL + (k0_), B0 + (buf) * 4096 + (w * 32 + 16) * 32); \
} while (0)

    GSTAGE(0, 0);
    GSTAGE(1, 32);
    int cur = 0;
    for (int k0 = 0; k0 < DMODEL; k0 += 32) {
        // current tile's loads complete; next tile's may stay in flight
        if (k0 + 32 < DMODEL)
            asm volatile("s_waitcnt vmcnt(4)" ::: "memory");
        else
            asm volatile("s_waitcnt vmcnt(0)" ::: "memory");
        __builtin_amdgcn_s_barrier();
        asm volatile("" ::: "memory");

        if (k0 + 64 < DMODEL) {
            int nb = cur + 2; if (nb >= 3) nb -= 3;
            GSTAGE(nb, k0 + 64);
        }

        const ushort_t* Ac = A0 + cur * 4096;
        const ushort_t* Bc = B0 + cur * 4096;
        bf16x8 a[4], b[4];
#pragma unroll
        for (int m = 0; m < 4; ++m)
            a[m] = *(const bf16x8*)&Ac[(wr * 64 + m * 16 + c) * 32 + g * 8];
#pragma unroll
        for (int n = 0; n < 4; ++n)
            b[n] = *(const bf16x8*)&Bc[(wc * 64 + n * 16 + c) * 32 + g * 8];
        __builtin_amdgcn_s_setprio(1);
#pragma unroll
        for (int m = 0; m < 4; ++m)
#pragma unroll
            for (int n = 0; n < 4; ++n)
                acc[m][n] = SWAP
                    ? __builtin_amdgcn_mfma_f32_16x16x32_bf16(b[n], a[m],
                                                              acc[m][n], 0, 0, 0)
                    : __builtin_amdgcn_mfma_f32_16x16x32_bf16(a[m], b[n],
                                                              acc[m][n], 0, 0, 0);
        __builtin_amdgcn_s_setprio(0);
        cur += 1; if (cur >= 3) cur -= 3;
    }
#undef GSTAGE
}

// ---------------------------------------------------------------------------
// Fused QKV. z=0: Q -> [B,H,T,DK] * (0.125*log2e), SWAP epilogue (uint2
// along dk). z=1: K -> [B,H,T,DK], SWAP. z=2: V -> [B,H,DK,T], non-SWAP
// (uint2 along t).
// ---------------------------------------------------------------------------
__global__ __launch_bounds__(256) void gemm_qkv_kernel(
    const ushort_t* __restrict__ Aq, const ushort_t* __restrict__ Ak,
    const ushort_t* __restrict__ Av, const ushort_t* __restrict__ Wq,
    const ushort_t* __restrict__ Wk, const ushort_t* __restrict__ Wv,
    const float* __restrict__ bq, const float* __restrict__ bk,
    const float* __restrict__ bv, ushort_t* __restrict__ Qo,
    ushort_t* __restrict__ Ko, ushort_t* __restrict__ VTo)
{
    __shared__ ushort_t Asm[3][4096];
    __shared__ ushort_t Bsm[3][4096];

    const int z = blockIdx.z;
    const ushort_t* A = (z == 0) ? Aq : (z == 1) ? Ak : Av;
    const ushort_t* W = (z == 0) ? Wq : (z == 1) ? Wk : Wv;
    const float* bias = (z == 0) ? bq : (z == 1) ? bk : bv;

    const int tid = threadIdx.x, w = tid >> 6, lane = tid & 63;
    const int c = lane & 15, g = lane >> 4;
    const int wr = w >> 1, wc = w & 1;
    const int row0 = blockIdx.y * 128, col0 = blockIdx.x * 128;

    f32x4 acc[4][4];
#pragma unroll
    for (int m = 0; m < 4; ++m)
#pragma unroll
        for (int n = 0; n < 4; ++n) acc[m][n] = (f32x4){0.f, 0.f, 0.f, 0.f};

    const int gc0 = col0 + wc * 64;

    if (z < 2) {
        gemm_body128<true>(A, W, Asm, Bsm, acc, row0, col0, w, lane);
        const float scale = (z == 0) ? QSCALE : 1.0f;
        ushort_t* O = (z == 0) ? Qo : Ko;
        float4 bias4[4];
#pragma unroll
        for (int n = 0; n < 4; ++n)
            bias4[n] = *(const float4*)&bias[gc0 + n * 16 + g * 4];
#pragma unroll
        for (int m = 0; m < 4; ++m) {
            const int gr = row0 + wr * 64 + m * 16 + c;
            const int bb = gr >> 11, t = gr & 2047;
#pragma unroll
            for (int n = 0; n < 4; ++n) {
                const int col = gc0 + n * 16 + g * 4;
                const int h = col >> 6, dk0 = col & 63;
                uint2 u;
                u.x = cvt_pk_bf16((acc[m][n][0] + bias4[n].x) * scale,
                                  (acc[m][n][1] + bias4[n].y) * scale);
                u.y = cvt_pk_bf16((acc[m][n][2] + bias4[n].z) * scale,
                                  (acc[m][n][3] + bias4[n].w) * scale);
                *(uint2*)&O[(((size_t)(bb * NHEADS + h) * TS + t) << 6) + dk0] = u;
            }
        }
    } else {
        gemm_body128<false>(A, W, Asm, Bsm, acc, row0, col0, w, lane);
        float bv4[4];
#pragma unroll
        for (int n = 0; n < 4; ++n) bv4[n] = bias[gc0 + n * 16 + c];
#pragma unroll
        for (int m = 0; m < 4; ++m) {
            const int gr0 = row0 + wr * 64 + m * 16 + g * 4;
            const int bb = gr0 >> 11, t0 = gr0 & 2047;
#pragma unroll
            for (int n = 0; n < 4; ++n) {
                const int gc = gc0 + n * 16 + c;
                const int h = gc >> 6, dk = gc & 63;
                uint2 u;
                u.x = cvt_pk_bf16(acc[m][n][0] + bv4[n],
                                  acc[m][n][1] + bv4[n]);
                u.y = cvt_pk_bf16(acc[m][n][2] + bv4[n],
                                  acc[m][n][3] + bv4[n]);
                *(uint2*)&VTo[((size_t)(bb * NHEADS + h) * DK + dk) * TS + t0] = u;
            }
        }
    }
}

// ---------------------------------------------------------------------------
// Output projection (SWAP): fp32 out [M][DMODEL], float4 stores.
// ---------------------------------------------------------------------------
__global__ __launch_bounds__(256) void gemm_out_kernel(
    const ushort_t* __restrict__ A, const ushort_t* __restrict__ W,
    const float* __restrict__ bias, float* __restrict__ Cout)
{
    __shared__ ushort_t Asm[3][4096];
    __shared__ ushort_t Bsm[3][4096];

    const int tid = threadIdx.x, w = tid >> 6, lane = tid & 63;
    const int c = lane & 15, g = lane >> 4;
    const int wr = w >> 1, wc = w & 1;
    const int row0 = blockIdx.y * 128, col0 = blockIdx.x * 128;

    f32x4 acc[4][4];
#pragma unroll
    for (int m = 0; m < 4; ++m)
#pragma unroll
        for (int n = 0; n < 4; ++n) acc[m][n] = (f32x4){0.f, 0.f, 0.f, 0.f};

    gemm_body128<true>(A, W, Asm, Bsm, acc, row0, col0, w, lane);

    const int gc0 = col0 + wc * 64;
    float4 bias4[4];
#pragma unroll
    for (int n = 0; n < 4; ++n)
        bias4[n] = *(const float4*)&bias[gc0 + n * 16 + g * 4];
#pragma unroll
    for (int m = 0; m < 4; ++m) {
        const int gr = row0 + wr * 64 + m * 16 + c;
#pragma unroll
        for (int n = 0; n < 4; ++n) {
            float4 cv;
            cv.x = acc[m][n][0] + bias4[n].x;
            cv.y = acc[m][n][1] + bias4[n].y;
            cv.z = acc[m][n][2] + bias4[n].z;
            cv.w = acc[m][n][3] + bias4[n].w;
            *(float4*)&Cout[(size_t)gr * DMODEL + gc0 + n * 16 + g * 4] = cv;
        }
    }
}

// ---------------------------------------------------------------------------
// Flash attention, swapped-operand MFMA. 4 waves x 32 q-rows (QBLK=128),
// KV tiles of 64. Q pre-scaled by 0.125*log2e -> exp2 softmax.
// K [B,H,T,DK], V^T [B,H,DK,T]. Defer-max (THR=8, log2 units).
// (unchanged from round 6 — passing, ~450 TF effective)
// ---------------------------------------------------------------------------
__global__ __launch_bounds__(256) void attn_bf16_kernel(
    const ushort_t* __restrict__ Q, const ushort_t* __restrict__ K,
    const ushort_t* __restrict__ VT, ushort_t* __restrict__ ctx)
{
    __shared__ ushort_t Ks[2][64 * 64];   // [s][d] swizzled, 8KB each
    __shared__ ushort_t Vt[2][64 * 64];   // [d][s] swizzled
    __shared__ ushort_t Ps[4][32 * 64];   // per-wave [q][s] swizzled

    const int tid = threadIdx.x;
    const int w = tid >> 6, lane = tid & 63;
    const int c = lane & 15, g = lane >> 4;
    const int sid = blockIdx.x;                    // 0..511
    const int bh = (sid & 7) | ((sid >> 7) << 3);  // 0..31
    const int qb = (sid >> 3) & 15;
    const int q0 = qb << 7;
    const size_t base = (size_t)bh * TS * DK;
    const ushort_t* Qp = Q + base;
    const ushort_t* Kp = K + base;
    const ushort_t* VTp = VT + base;  // [DK][TS]

    const int lrow8 = lane >> 3;
    const int lc16 = lane & 7;
    const int scol = (lc16 ^ lrow8) << 3;  // pre-swizzled source granule
    const ushort_t* Kg = Kp + (size_t)(w * 16 + lrow8) * DK + scol;
    const ushort_t* Vg = VTp + (size_t)(w * 16 + lrow8) * TS + scol;

#define STAGE(buf, s0_) do { \
    gload_lds16(Kg + (size_t)(s0_) * DK, &Ks[buf][(w * 16) * 64]); \
    gload_lds16(Kg + (size_t)((s0_) + 8) * DK, &Ks[buf][(w * 16 + 8) * 64]); \
    gload_lds16(Vg + (s0_), &Vt[buf][(w * 16) * 64]); \
    gload_lds16(Vg + (s0_) + 8 * TS, &Vt[buf][(w * 16 + 8) * 64]); \
} while (0)

    bf16x8 qa[2][2];
#pragma unroll
    for (int qh = 0; qh < 2; ++qh) {
        const ushort_t* qrow = Qp + (size_t)(q0 + w * 32 + qh * 16 + c) * DK;
        qa[qh][0] = *(const bf16x8*)(qrow + g * 8);
        qa[qh][1] = *(const bf16x8*)(qrow + 32 + g * 8);
    }

    float m_i[2] = {-1e30f, -1e30f}, l_i[2] = {0.f, 0.f};
    f32x4 o[2][4];
#pragma unroll
    for (int qh = 0; qh < 2; ++qh)
#pragma unroll
        for (int df = 0; df < 4; ++df) o[qh][df] = (f32x4){0.f, 0.f, 0.f, 0.f};

    const int cs = (c & 7) << 4;
    char* Pw0 = (char*)&Ps[w][0];

    STAGE(0, 0);
    __syncthreads();
    int cur = 0;

    for (int s0 = 0; s0 < TS; s0 += 64) {
        if (s0 + 64 < TS) STAGE(cur ^ 1, s0 + 64);

        const char* Kb = (const char*)&Ks[cur][0];
        const char* Vb = (const char*)&Vt[cur][0];

        f32x4 sf[2][4];
#pragma unroll
        for (int qh = 0; qh < 2; ++qh)
#pragma unroll
            for (int fc = 0; fc < 4; ++fc) sf[qh][fc] = (f32x4){0.f, 0.f, 0.f, 0.f};
#pragma unroll
        for (int fc = 0; fc < 4; ++fc) {
#pragma unroll
            for (int ch = 0; ch < 2; ++ch) {
                const bf16x8 kb = *(const bf16x8*)(Kb + (fc * 16 + c) * 128 +
                                                   ((ch * 64 + g * 16) ^ cs));
                __builtin_amdgcn_s_setprio(1);
                sf[0][fc] = __builtin_amdgcn_mfma_f32_16x16x32_bf16(kb, qa[0][ch],
                                                                    sf[0][fc], 0, 0, 0);
                sf[1][fc] = __builtin_amdgcn_mfma_f32_16x16x32_bf16(kb, qa[1][ch],
                                                                    sf[1][fc], 0, 0, 0);
                __builtin_amdgcn_s_setprio(0);
            }
        }

        float mt[2];
#pragma unroll
        for (int qh = 0; qh < 2; ++qh) {
            float a0 = fmaxf(fmaxf(sf[qh][0][0], sf[qh][0][1]),
                             fmaxf(sf[qh][0][2], sf[qh][0][3]));
            float a1 = fmaxf(fmaxf(sf[qh][1][0], sf[qh][1][1]),
                             fmaxf(sf[qh][1][2], sf[qh][1][3]));
            float a2 = fmaxf(fmaxf(sf[qh][2][0], sf[qh][2][1]),
                             fmaxf(sf[qh][2][2], sf[qh][2][3]));
            float a3 = fmaxf(fmaxf(sf[qh][3][0], sf[qh][3][1]),
                             fmaxf(sf[qh][3][2], sf[qh][3][3]));
            float m = fmaxf(fmaxf(a0, a1), fmaxf(a2, a3));
            m = fmaxf(m, __shfl_xor(m, 16));
            m = fmaxf(m, __shfl_xor(m, 32));
            mt[qh] = m;
        }

        // defer-max (T13): values are log2-scale; p bounded by 2^8
        const int defer = (mt[0] <= m_i[0] + 8.f) && (mt[1] <= m_i[1] + 8.f);
        if (!__all(defer)) {
#pragma unroll
            for (int qh = 0; qh < 2; ++qh) {
                const float mn = fmaxf(m_i[qh], mt[qh]);
                const float fs = __builtin_amdgcn_exp2f(m_i[qh] - mn);
                m_i[qh] = mn;
                l_i[qh] *= fs;
#pragma unroll
                for (int df = 0; df < 4; ++df)
#pragma unroll
                    for (int r = 0; r < 4; ++r) o[qh][df][r] *= fs;
            }
        }

#pragma unroll
        for (int qh = 0; qh < 2; ++qh) {
            char* Pw = Pw0 + (qh * 16 + c) * 128;
            float rs = 0.f;
#pragma unroll
            for (int fc = 0; fc < 4; ++fc) {
                float p0 = __builtin_amdgcn_exp2f(sf[qh][fc][0] - m_i[qh]);
                float p1 = __builtin_amdgcn_exp2f(sf[qh][fc][1] - m_i[qh]);
                float p2 = __builtin_amdgcn_exp2f(sf[qh][fc][2] - m_i[qh]);
                float p3 = __builtin_amdgcn_exp2f(sf[qh][fc][3] - m_i[qh]);
                rs += (p0 + p1) + (p2 + p3);
                uint2 u;
                u.x = cvt_pk_bf16(p0, p1);
                u.y = cvt_pk_bf16(p2, p3);
                *(uint2*)(Pw + ((fc * 32 + g * 8) ^ cs)) = u;
            }
            rs += __shfl_xor(rs, 16);
            rs += __shfl_xor(rs, 32);
            l_i[qh] += rs;
        }

#pragma unroll
        for (int ch = 0; ch < 2; ++ch) {
            const bf16x8 pb0 = *(const bf16x8*)(Pw0 + c * 128 +
                                                ((ch * 64 + g * 16) ^ cs));
            const bf16x8 pb1 = *(const bf16x8*)(Pw0 + (16 + c) * 128 +
                                                ((ch * 64 + g * 16) ^ cs));
#pragma unroll
            for (int df = 0; df < 4; ++df) {
                const bf16x8 vb = *(const bf16x8*)(Vb + (df * 16 + c) * 128 +
                                                   ((ch * 64 + g * 16) ^ cs));
                __builtin_amdgcn_s_setprio(1);
                o[0][df] = __builtin_amdgcn_mfma_f32_16x16x32_bf16(vb, pb0,
                                                                   o[0][df], 0, 0, 0);
                o[1][df] = __builtin_amdgcn_mfma_f32_16x16x32_bf16(vb, pb1,
                                                                   o[1][df], 0, 0, 0);
                __builtin_amdgcn_s_setprio(0);
            }
        }
        __syncthreads();
        cur ^= 1;
    }
#undef STAGE

    const int bb = bh >> 4, h = bh & 15;
#pragma unroll
    for (int qh = 0; qh < 2; ++qh) {
        const float inv = 1.0f / l_i[qh];
        const int t = q0 + w * 32 + qh * 16 + c;
        ushort_t* crow = ctx + ((size_t)(bb * TS + t) * DMODEL + h * 64 + g * 4);
#pragma unroll
        for (int df = 0; df < 4; ++df) {
            uint2 u;
            u.x = cvt_pk_bf16(o[qh][df][0] * inv, o[qh][df][1] * inv);
            u.y = cvt_pk_bf16(o[qh][df][2] * inv, o[qh][df][3] * inv);
            *(uint2*)(crow + df * 16) = u;
        }
    }
}

// ---------------------------------------------------------------------------
extern "C" void kernel_launch(void* const* d_in, const int* in_sizes, int n_in,
                              void* d_out, int out_size, void* d_ws, size_t ws_size,
                              hipStream_t stream)
{
    const float* query  = (const float*)d_in[0];
    const float* key_in = (const float*)d_in[1];
    const float* value  = (const float*)d_in[2];
    const float* Wq = (const float*)d_in[3];
    const float* bq = (const float*)d_in[4];
    const float* Wk = (const float*)d_in[5];
    const float* bk = (const float*)d_in[6];
    const float* Wv = (const float*)d_in[7];
    const float* bv = (const float*)d_in[8];
    const float* Wo = (const float*)d_in[9];
    const float* bo = (const float*)d_in[10];

    ushort_t* W16 = (ushort_t*)d_ws;
    const size_t M1 = 1u << 20;
    ushort_t* qi  = W16;             // bf16 activations
    ushort_t* ki  = W16 + 4 * M1;
    ushort_t* vi  = W16 + 8 * M1;
    ushort_t* wqb = W16 + 12 * M1;   // bf16 weights
    ushort_t* wkb = W16 + 13 * M1;
    ushort_t* wvb = W16 + 14 * M1;
    ushort_t* wob = W16 + 15 * M1;
    ushort_t* Qp  = W16 + 16 * M1;   // Q [B,H,T,DK] (pre-scaled)
    ushort_t* Kp  = W16 + 20 * M1;   // K [B,H,T,DK]
    ushort_t* VpT = W16 + 24 * M1;   // V^T [B,H,DK,T]
    ushort_t* cb  = W16 + 28 * M1;   // ctx bf16 [B,T,DMODEL]

    cvt_all_kernel<<<16384, 256, 0, stream>>>(query, key_in, value,
                                              Wq, Wk, Wv, Wo, W16);

    gemm_qkv_kernel<<<dim3(8, 32, 3), 256, 0, stream>>>(
        qi, ki, vi, wqb, wkb, wvb, bq, bk, bv, Qp, Kp, VpT);

    attn_bf16_kernel<<<512, 256, 0, stream>>>(Qp, Kp, VpT, cb);

    gemm_out_kernel<<<dim3(8, 32), 256, 0, stream>>>(cb, wob, bo, (float*)d_out);
}

// Round 8
// 259.601 us; speedup vs baseline: 1.0102x; 1.0102x over previous
//
#include <hip/hip_runtime.h>

typedef unsigned short ushort_t;
typedef __attribute__((ext_vector_type(8))) short bf16x8;
typedef __attribute__((ext_vector_type(4))) float f32x4;

#define DMODEL 1024
#define NHEADS 16
#define DK 64
#define BS 2
#define TS 2048
#define MROWS (BS * TS)  // 4096

// 0.125 * log2(e): folded into Q so attention uses raw v_exp_f32 (exp2)
#define QSCALE 0.1803368801111204f

__device__ __forceinline__ ushort_t f2bf(float x) {
    unsigned u = __float_as_uint(x);
    return (ushort_t)((u + 0x7FFFu + ((u >> 16) & 1u)) >> 16);  // RNE
}

__device__ __forceinline__ unsigned cvt_pk_bf16(float lo, float hi) {
    unsigned r;
    asm("v_cvt_pk_bf16_f32 %0, %1, %2" : "=v"(r) : "v"(lo), "v"(hi));
    return r;
}

__device__ __forceinline__ void gload_lds16(const void* g, void* l) {
    __builtin_amdgcn_global_load_lds(
        (const __attribute__((address_space(1))) unsigned*)g,
        (__attribute__((address_space(3))) unsigned*)l, 16, 0, 0);
}

// ---------------------------------------------------------------------------
// fp32 -> bf16 cast: 3 activations (4M each) + 4 weights (1M each).
// ---------------------------------------------------------------------------
__global__ __launch_bounds__(256) void cvt_all_kernel(
    const float* __restrict__ q, const float* __restrict__ k,
    const float* __restrict__ v, const float* __restrict__ wq,
    const float* __restrict__ wk, const float* __restrict__ wv,
    const float* __restrict__ wo, ushort_t* __restrict__ dst)
{
    const int i = blockIdx.x * 256 + threadIdx.x;  // float4 index
    const float4* s;
    int off;
    if (i < (1 << 20))      { s = (const float4*)q; off = i; }
    else if (i < (2 << 20)) { s = (const float4*)k; off = i - (1 << 20); }
    else if (i < (3 << 20)) { s = (const float4*)v; off = i - (2 << 20); }
    else {
        const int j = i - (3 << 20);
        const int w = j >> 18;
        off = j & 0x3FFFF;
        s = (w == 0) ? (const float4*)wq : (w == 1) ? (const float4*)wk
          : (w == 2) ? (const float4*)wv : (const float4*)wo;
    }
    const float4 x = s[off];
    ushort4 o;
    o.x = f2bf(x.x); o.y = f2bf(x.y); o.z = f2bf(x.z); o.w = f2bf(x.w);
    ((ushort4*)dst)[i] = o;
}

// ---------------------------------------------------------------------------
// GEMM core, occupancy-first: BM=64, BN = NB*32 (NB=4 -> 128, NB=2 -> 64).
// 4 waves in 2x2; wave tile 32 x NB*16. BK=32, 2-phase dbuf LDS, one
// __syncthreads per k-step. A-tile = exactly 1 global_load_lds per wave.
// SWAP=false: acc = mfma(a, b) -> lane holds C[t-frag=g4r][col=c]
// SWAP=true : acc = mfma(b, a) -> lane holds C[t=c][col-frag=g4r]
// ---------------------------------------------------------------------------
template <int NB, bool SWAP>
__device__ __forceinline__ void gemm_body64(
    const ushort_t* __restrict__ A, const ushort_t* __restrict__ W,
    ushort_t* __restrict__ Asm, ushort_t* __restrict__ Bsm,
    f32x4 (&acc)[2][NB], int row0, int col0, int w, int lane)
{
    const int c = lane & 15, g = lane >> 4;
    const int wr = w & 1, wc = w >> 1;
    const int lr = lane >> 2;          // 0..15 staging row within 16-chunk
    const int lcb = (lane & 3) * 8;    // 16B chunk within 64B row
    const ushort_t* Ab = &A[(size_t)(row0 + w * 16 + lr) * DMODEL + lcb];
    const ushort_t* Wb = &W[(size_t)(col0 + w * (NB * 8) + lr) * DMODEL + lcb];
    const int BSTRIDE = NB * 1024;     // ushorts per B buffer

#define GSTAGE(buf, k0_) do { \
    gload_lds16(Ab + (k0_), Asm + (buf) * 2048 + (w * 16) * 32); \
    gload_lds16(Wb + (k0_), Bsm + (buf) * BSTRIDE + (w * (NB * 8)) * 32); \
    if (NB == 4) \
        gload_lds16(Wb + 16 * DMODEL + (k0_), \
                    Bsm + (buf) * BSTRIDE + (w * 32 + 16) * 32); \
} while (0)

    GSTAGE(0, 0);
    __syncthreads();
    int cur = 0;
    for (int k0 = 0; k0 < DMODEL; k0 += 32) {
        if (k0 + 32 < DMODEL) GSTAGE(cur ^ 1, k0 + 32);
        const ushort_t* Ac = Asm + cur * 2048;
        const ushort_t* Bc = Bsm + cur * BSTRIDE;
        bf16x8 a[2], b[NB];
#pragma unroll
        for (int m = 0; m < 2; ++m)
            a[m] = *(const bf16x8*)&Ac[(wr * 32 + m * 16 + c) * 32 + g * 8];
#pragma unroll
        for (int n = 0; n < NB; ++n)
            b[n] = *(const bf16x8*)&Bc[(wc * (NB * 16) + n * 16 + c) * 32 + g * 8];
        __builtin_amdgcn_s_setprio(1);
#pragma unroll
        for (int m = 0; m < 2; ++m)
#pragma unroll
            for (int n = 0; n < NB; ++n)
                acc[m][n] = SWAP
                    ? __builtin_amdgcn_mfma_f32_16x16x32_bf16(b[n], a[m],
                                                              acc[m][n], 0, 0, 0)
                    : __builtin_amdgcn_mfma_f32_16x16x32_bf16(a[m], b[n],
                                                              acc[m][n], 0, 0, 0);
        __builtin_amdgcn_s_setprio(0);
        __syncthreads();
        cur ^= 1;
    }
#undef GSTAGE
}

// ---------------------------------------------------------------------------
// Fused QKV (BM=64, BN=128, grid (8,64,3) = 1536 blocks = 6/CU).
// z=0: Q -> [B,H,T,DK] * (0.125*log2e), SWAP. z=1: K -> [B,H,T,DK], SWAP.
// z=2: V -> [B,H,DK,T], non-SWAP (uint2 along t).
// ---------------------------------------------------------------------------
__global__ __launch_bounds__(256) void gemm_qkv_kernel(
    const ushort_t* __restrict__ Aq, const ushort_t* __restrict__ Ak,
    const ushort_t* __restrict__ Av, const ushort_t* __restrict__ Wq,
    const ushort_t* __restrict__ Wk, const ushort_t* __restrict__ Wv,
    const float* __restrict__ bq, const float* __restrict__ bk,
    const float* __restrict__ bv, ushort_t* __restrict__ Qo,
    ushort_t* __restrict__ Ko, ushort_t* __restrict__ VTo)
{
    __shared__ ushort_t Asm[2][2048];
    __shared__ ushort_t Bsm[2][4096];

    const int z = blockIdx.z;
    const ushort_t* A = (z == 0) ? Aq : (z == 1) ? Ak : Av;
    const ushort_t* W = (z == 0) ? Wq : (z == 1) ? Wk : Wv;
    const float* bias = (z == 0) ? bq : (z == 1) ? bk : bv;

    const int tid = threadIdx.x, w = tid >> 6, lane = tid & 63;
    const int c = lane & 15, g = lane >> 4;
    const int wr = w & 1, wc = w >> 1;
    const int row0 = blockIdx.y * 64, col0 = blockIdx.x * 128;

    f32x4 acc[2][4];
#pragma unroll
    for (int m = 0; m < 2; ++m)
#pragma unroll
        for (int n = 0; n < 4; ++n) acc[m][n] = (f32x4){0.f, 0.f, 0.f, 0.f};

    const int gc0 = col0 + wc * 64;

    if (z < 2) {
        gemm_body64<4, true>(A, W, &Asm[0][0], &Bsm[0][0], acc, row0, col0, w, lane);
        const float scale = (z == 0) ? QSCALE : 1.0f;
        ushort_t* O = (z == 0) ? Qo : Ko;
        float4 bias4[4];
#pragma unroll
        for (int n = 0; n < 4; ++n)
            bias4[n] = *(const float4*)&bias[gc0 + n * 16 + g * 4];
#pragma unroll
        for (int m = 0; m < 2; ++m) {
            const int gr = row0 + wr * 32 + m * 16 + c;
            const int bb = gr >> 11, t = gr & 2047;
#pragma unroll
            for (int n = 0; n < 4; ++n) {
                const int col = gc0 + n * 16 + g * 4;
                const int h = col >> 6, dk0 = col & 63;
                uint2 u;
                u.x = cvt_pk_bf16((acc[m][n][0] + bias4[n].x) * scale,
                                  (acc[m][n][1] + bias4[n].y) * scale);
                u.y = cvt_pk_bf16((acc[m][n][2] + bias4[n].z) * scale,
                                  (acc[m][n][3] + bias4[n].w) * scale);
                *(uint2*)&O[(((size_t)(bb * NHEADS + h) * TS + t) << 6) + dk0] = u;
            }
        }
    } else {
        gemm_body64<4, false>(A, W, &Asm[0][0], &Bsm[0][0], acc, row0, col0, w, lane);
        float bv4[4];
#pragma unroll
        for (int n = 0; n < 4; ++n) bv4[n] = bias[gc0 + n * 16 + c];
#pragma unroll
        for (int m = 0; m < 2; ++m) {
            const int gr0 = row0 + wr * 32 + m * 16 + g * 4;
            const int bb = gr0 >> 11, t0 = gr0 & 2047;
#pragma unroll
            for (int n = 0; n < 4; ++n) {
                const int gc = gc0 + n * 16 + c;
                const int h = gc >> 6, dk = gc & 63;
                uint2 u;
                u.x = cvt_pk_bf16(acc[m][n][0] + bv4[n],
                                  acc[m][n][1] + bv4[n]);
                u.y = cvt_pk_bf16(acc[m][n][2] + bv4[n],
                                  acc[m][n][3] + bv4[n]);
                *(uint2*)&VTo[((size_t)(bb * NHEADS + h) * DK + dk) * TS + t0] = u;
            }
        }
    }
}

// ---------------------------------------------------------------------------
// Output projection (BM=64, BN=64, grid (16,64) = 1024 blocks = 4/CU).
// SWAP epilogue, fp32 out [M][DMODEL], float4 stores.
// ---------------------------------------------------------------------------
__global__ __launch_bounds__(256) void gemm_out_kernel(
    const ushort_t* __restrict__ A, const ushort_t* __restrict__ W,
    const float* __restrict__ bias, float* __restrict__ Cout)
{
    __shared__ ushort_t Asm[2][2048];
    __shared__ ushort_t Bsm[2][2048];

    const int tid = threadIdx.x, w = tid >> 6, lane = tid & 63;
    const int c = lane & 15, g = lane >> 4;
    const int wr = w & 1, wc = w >> 1;
    const int row0 = blockIdx.y * 64, col0 = blockIdx.x * 64;

    f32x4 acc[2][2];
#pragma unroll
    for (int m = 0; m < 2; ++m)
#pragma unroll
        for (int n = 0; n < 2; ++n) acc[m][n] = (f32x4){0.f, 0.f, 0.f, 0.f};

    gemm_body64<2, true>(A, W, &Asm[0][0], &Bsm[0][0], acc, row0, col0, w, lane);

    const int gc0 = col0 + wc * 32;
    float4 bias4[2];
#pragma unroll
    for (int n = 0; n < 2; ++n)
        bias4[n] = *(const float4*)&bias[gc0 + n * 16 + g * 4];
#pragma unroll
    for (int m = 0; m < 2; ++m) {
        const int gr = row0 + wr * 32 + m * 16 + c;
#pragma unroll
        for (int n = 0; n < 2; ++n) {
            float4 cv;
            cv.x = acc[m][n][0] + bias4[n].x;
            cv.y = acc[m][n][1] + bias4[n].y;
            cv.z = acc[m][n][2] + bias4[n].z;
            cv.w = acc[m][n][3] + bias4[n].w;
            *(float4*)&Cout[(size_t)gr * DMODEL + gc0 + n * 16 + g * 4] = cv;
        }
    }
}

// ---------------------------------------------------------------------------
// Flash attention, swapped-operand MFMA. 4 waves x 32 q-rows (QBLK=128),
// KV tiles of 64. Q pre-scaled by 0.125*log2e -> exp2 softmax.
// K [B,H,T,DK], V^T [B,H,DK,T]. Defer-max (THR=8, log2 units).
// (unchanged — passing, ~450 TF effective)
// ---------------------------------------------------------------------------
__global__ __launch_bounds__(256) void attn_bf16_kernel(
    const ushort_t* __restrict__ Q, const ushort_t* __restrict__ K,
    const ushort_t* __restrict__ VT, ushort_t* __restrict__ ctx)
{
    __shared__ ushort_t Ks[2][64 * 64];   // [s][d] swizzled, 8KB each
    __shared__ ushort_t Vt[2][64 * 64];   // [d][s] swizzled
    __shared__ ushort_t Ps[4][32 * 64];   // per-wave [q][s] swizzled

    const int tid = threadIdx.x;
    const int w = tid >> 6, lane = tid & 63;
    const int c = lane & 15, g = lane >> 4;
    const int sid = blockIdx.x;                    // 0..511
    const int bh = (sid & 7) | ((sid >> 7) << 3);  // 0..31
    const int qb = (sid >> 3) & 15;
    const int q0 = qb << 7;
    const size_t base = (size_t)bh * TS * DK;
    const ushort_t* Qp = Q + base;
    const ushort_t* Kp = K + base;
    const ushort_t* VTp = VT + base;  // [DK][TS]

    const int lrow8 = lane >> 3;
    const int lc16 = lane & 7;
    const int scol = (lc16 ^ lrow8) << 3;  // pre-swizzled source granule
    const ushort_t* Kg = Kp + (size_t)(w * 16 + lrow8) * DK + scol;
    const ushort_t* Vg = VTp + (size_t)(w * 16 + lrow8) * TS + scol;

#define STAGE(buf, s0_) do { \
    gload_lds16(Kg + (size_t)(s0_) * DK, &Ks[buf][(w * 16) * 64]); \
    gload_lds16(Kg + (size_t)((s0_) + 8) * DK, &Ks[buf][(w * 16 + 8) * 64]); \
    gload_lds16(Vg + (s0_), &Vt[buf][(w * 16) * 64]); \
    gload_lds16(Vg + (s0_) + 8 * TS, &Vt[buf][(w * 16 + 8) * 64]); \
} while (0)

    bf16x8 qa[2][2];
#pragma unroll
    for (int qh = 0; qh < 2; ++qh) {
        const ushort_t* qrow = Qp + (size_t)(q0 + w * 32 + qh * 16 + c) * DK;
        qa[qh][0] = *(const bf16x8*)(qrow + g * 8);
        qa[qh][1] = *(const bf16x8*)(qrow + 32 + g * 8);
    }

    float m_i[2] = {-1e30f, -1e30f}, l_i[2] = {0.f, 0.f};
    f32x4 o[2][4];
#pragma unroll
    for (int qh = 0; qh < 2; ++qh)
#pragma unroll
        for (int df = 0; df < 4; ++df) o[qh][df] = (f32x4){0.f, 0.f, 0.f, 0.f};

    const int cs = (c & 7) << 4;
    char* Pw0 = (char*)&Ps[w][0];

    STAGE(0, 0);
    __syncthreads();
    int cur = 0;

    for (int s0 = 0; s0 < TS; s0 += 64) {
        if (s0 + 64 < TS) STAGE(cur ^ 1, s0 + 64);

        const char* Kb = (const char*)&Ks[cur][0];
        const char* Vb = (const char*)&Vt[cur][0];

        f32x4 sf[2][4];
#pragma unroll
        for (int qh = 0; qh < 2; ++qh)
#pragma unroll
            for (int fc = 0; fc < 4; ++fc) sf[qh][fc] = (f32x4){0.f, 0.f, 0.f, 0.f};
#pragma unroll
        for (int fc = 0; fc < 4; ++fc) {
#pragma unroll
            for (int ch = 0; ch < 2; ++ch) {
                const bf16x8 kb = *(const bf16x8*)(Kb + (fc * 16 + c) * 128 +
                                                   ((ch * 64 + g * 16) ^ cs));
                __builtin_amdgcn_s_setprio(1);
                sf[0][fc] = __builtin_amdgcn_mfma_f32_16x16x32_bf16(kb, qa[0][ch],
                                                                    sf[0][fc], 0, 0, 0);
                sf[1][fc] = __builtin_amdgcn_mfma_f32_16x16x32_bf16(kb, qa[1][ch],
                                                                    sf[1][fc], 0, 0, 0);
                __builtin_amdgcn_s_setprio(0);
            }
        }

        float mt[2];
#pragma unroll
        for (int qh = 0; qh < 2; ++qh) {
            float a0 = fmaxf(fmaxf(sf[qh][0][0], sf[qh][0][1]),
                             fmaxf(sf[qh][0][2], sf[qh][0][3]));
            float a1 = fmaxf(fmaxf(sf[qh][1][0], sf[qh][1][1]),
                             fmaxf(sf[qh][1][2], sf[qh][1][3]));
            float a2 = fmaxf(fmaxf(sf[qh][2][0], sf[qh][2][1]),
                             fmaxf(sf[qh][2][2], sf[qh][2][3]));
            float a3 = fmaxf(fmaxf(sf[qh][3][0], sf[qh][3][1]),
                             fmaxf(sf[qh][3][2], sf[qh][3][3]));
            float m = fmaxf(fmaxf(a0, a1), fmaxf(a2, a3));
            m = fmaxf(m, __shfl_xor(m, 16));
            m = fmaxf(m, __shfl_xor(m, 32));
            mt[qh] = m;
        }

        // defer-max (T13): values are log2-scale; p bounded by 2^8
        const int defer = (mt[0] <= m_i[0] + 8.f) && (mt[1] <= m_i[1] + 8.f);
        if (!__all(defer)) {
#pragma unroll
            for (int qh = 0; qh < 2; ++qh) {
                const float mn = fmaxf(m_i[qh], mt[qh]);
                const float fs = __builtin_amdgcn_exp2f(m_i[qh] - mn);
                m_i[qh] = mn;
                l_i[qh] *= fs;
#pragma unroll
                for (int df = 0; df < 4; ++df)
#pragma unroll
                    for (int r = 0; r < 4; ++r) o[qh][df][r] *= fs;
            }
        }

#pragma unroll
        for (int qh = 0; qh < 2; ++qh) {
            char* Pw = Pw0 + (qh * 16 + c) * 128;
            float rs = 0.f;
#pragma unroll
            for (int fc = 0; fc < 4; ++fc) {
                float p0 = __builtin_amdgcn_exp2f(sf[qh][fc][0] - m_i[qh]);
                float p1 = __builtin_amdgcn_exp2f(sf[qh][fc][1] - m_i[qh]);
                float p2 = __builtin_amdgcn_exp2f(sf[qh][fc][2] - m_i[qh]);
                float p3 = __builtin_amdgcn_exp2f(sf[qh][fc][3] - m_i[qh]);
                rs += (p0 + p1) + (p2 + p3);
                uint2 u;
                u.x = cvt_pk_bf16(p0, p1);
                u.y = cvt_pk_bf16(p2, p3);
                *(uint2*)(Pw + ((fc * 32 + g * 8) ^ cs)) = u;
            }
            rs += __shfl_xor(rs, 16);
            rs += __shfl_xor(rs, 32);
            l_i[qh] += rs;
        }

#pragma unroll
        for (int ch = 0; ch < 2; ++ch) {
            const bf16x8 pb0 = *(const bf16x8*)(Pw0 + c * 128 +
                                                ((ch * 64 + g * 16) ^ cs));
            const bf16x8 pb1 = *(const bf16x8*)(Pw0 + (16 + c) * 128 +
                                                ((ch * 64 + g * 16) ^ cs));
#pragma unroll
            for (int df = 0; df < 4; ++df) {
                const bf16x8 vb = *(const bf16x8*)(Vb + (df * 16 + c) * 128 +
                                                   ((ch * 64 + g * 16) ^ cs));
                __builtin_amdgcn_s_setprio(1);
                o[0][df] = __builtin_amdgcn_mfma_f32_16x16x32_bf16(vb, pb0,
                                                                   o[0][df], 0, 0, 0);
                o[1][df] = __builtin_amdgcn_mfma_f32_16x16x32_bf16(vb, pb1,
                                                                   o[1][df], 0, 0, 0);
                __builtin_amdgcn_s_setprio(0);
            }
        }
        __syncthreads();
        cur ^= 1;
    }
#undef STAGE

    const int bb = bh >> 4, h = bh & 15;
#pragma unroll
    for (int qh = 0; qh < 2; ++qh) {
        const float inv = 1.0f / l_i[qh];
        const int t = q0 + w * 32 + qh * 16 + c;
        ushort_t* crow = ctx + ((size_t)(bb * TS + t) * DMODEL + h * 64 + g * 4);
#pragma unroll
        for (int df = 0; df < 4; ++df) {
            uint2 u;
            u.x = cvt_pk_bf16(o[qh][df][0] * inv, o[qh][df][1] * inv);
            u.y = cvt_pk_bf16(o[qh][df][2] * inv, o[qh][df][3] * inv);
            *(uint2*)(crow + df * 16) = u;
        }
    }
}

// ---------------------------------------------------------------------------
extern "C" void kernel_launch(void* const* d_in, const int* in_sizes, int n_in,
                              void* d_out, int out_size, void* d_ws, size_t ws_size,
                              hipStream_t stream)
{
    const float* query  = (const float*)d_in[0];
    const float* key_in = (const float*)d_in[1];
    const float* value  = (const float*)d_in[2];
    const float* Wq = (const float*)d_in[3];
    const float* bq = (const float*)d_in[4];
    const float* Wk = (const float*)d_in[5];
    const float* bk = (const float*)d_in[6];
    const float* Wv = (const float*)d_in[7];
    const float* bv = (const float*)d_in[8];
    const float* Wo = (const float*)d_in[9];
    const float* bo = (const float*)d_in[10];

    ushort_t* W16 = (ushort_t*)d_ws;
    const size_t M1 = 1u << 20;
    ushort_t* qi  = W16;             // bf16 activations
    ushort_t* ki  = W16 + 4 * M1;
    ushort_t* vi  = W16 + 8 * M1;
    ushort_t* wqb = W16 + 12 * M1;   // bf16 weights
    ushort_t* wkb = W16 + 13 * M1;
    ushort_t* wvb = W16 + 14 * M1;
    ushort_t* wob = W16 + 15 * M1;
    ushort_t* Qp  = W16 + 16 * M1;   // Q [B,H,T,DK] (pre-scaled)
    ushort_t* Kp  = W16 + 20 * M1;   // K [B,H,T,DK]
    ushort_t* VpT = W16 + 24 * M1;   // V^T [B,H,DK,T]
    ushort_t* cb  = W16 + 28 * M1;   // ctx bf16 [B,T,DMODEL]

    cvt_all_kernel<<<16384, 256, 0, stream>>>(query, key_in, value,
                                              Wq, Wk, Wv, Wo, W16);

    gemm_qkv_kernel<<<dim3(8, 64, 3), 256, 0, stream>>>(
        qi, ki, vi, wqb, wkb, wvb, bq, bk, bv, Qp, Kp, VpT);

    attn_bf16_kernel<<<512, 256, 0, stream>>>(Qp, Kp, VpT, cb);

    gemm_out_kernel<<<dim3(16, 64), 256, 0, stream>>>(cb, wob, bo, (float*)d_out);
}